// Round 18
// baseline (217.784 us; speedup 1.0000x reference)
//
#include <hip/hip_runtime.h>

// UpCaps fused: transposed lanes, b-pair conv, XCD swizzle + ROUTE_QUAD.
// R18 delta vs R16 (126.8us best): the two independent route_pair calls are
// merged into one route_quad -- 4 pixels' routing chains interleaved in one
// scheduling region, doubling the independent DS-shuffle chains available to
// hide the 3-deep shfl latency in squash + logit-update. Peak live ~140 VGPR
// (votes 64 + lg 32 + sl 32 + temps) < (256,3) cap 168.
// R17 lesson: source-level prefetch is re-sunk by the scheduler (VGPR stayed
// 84) -- don't fight the compiler on load placement.
// R16 keeps: bijective XCD swizzle tile=(bid%8)*288+bid/8 (x ~1.4MB
// L2-resident/XCD; FETCH 14.7->6.4MB). R15: no pk_fma asm (half-rate fp32).
// OCCUPANCY LEDGER: (256,3)->84 VGPR clean; (256,4)->64-bucket spill;
// (256,5)/(512,8)->catastrophic spill. Keep (256,3).
// lane = a*8 + cg. Softmax over b lane-local; squash over a-lanes
// (xor 8,16,32); logit update over cg-lanes (xor 1,2,4). Output via 8KB LDS
// transpose -> 64B-line stores.
// Shapes: x(8,16,96,96), w(5,5,16,8,16), out(8,16,192,192).
typedef float v2f __attribute__((ext_vector_type(2)));

#define XH 96
#define XW 96
#define CIN 16
#define NA 8
#define NC 16
#define OH 192
#define OW 192
#define WP 102                        // padded width: ix in [-1,100] -> ixp 0..101
#define PADN (CIN * XH * WP * 8)      // 1,253,376 floats
#define NTILES ((OH * OW) / 16)       // 2304 = 8 XCDs x 288

__global__ __launch_bounds__(256) void pad_x(const float* __restrict__ x,
                                             float* __restrict__ xp) {
  int idx = blockIdx.x * 256 + threadIdx.x;
  if (idx >= PADN) return;
  int pos = idx & 7;                    // b-interleaved: pos = 2*bp + h
  int b   = (pos >> 1) + ((pos & 1) << 2);   // b = bp + 4h
  int t   = idx >> 3;
  int ixp = t % WP;
  int t2  = t / WP;
  int iy  = t2 % XH;
  int ci  = t2 / XH;
  int ix  = ixp - 1;
  float v = 0.f;
  if (ix >= 0 && ix < XW)
    v = x[((b * CIN + ci) * XH + iy) * XW + ix];
  xp[idx] = v;
}

// routes FOUR pixels' dynamic-routing loops fully interleaved.
// v[p][b] = votes (c-pair for this lane's (a, 2cg..2cg+1)) of pixel p.
// On exit q[p] = final squashed preds (c-pair).
__device__ __forceinline__ void route_quad(
    const v2f (&v)[4][8], int R, v2f (&q)[4])
{
  float lg[4][8];
#pragma unroll
  for (int p = 0; p < 4; ++p)
#pragma unroll
    for (int b = 0; b < 8; ++b) lg[p][b] = 0.f;

#pragma unroll 1
  for (int r = 0; r < R; ++r) {
    float sl[4][8];
    if (r == 0) {
#pragma unroll
      for (int p = 0; p < 4; ++p)
#pragma unroll
        for (int b = 0; b < 8; ++b) sl[p][b] = 0.125f;
    } else {
      // softmax over batch: lane-local, 4 independent chains
      float m[4], s[4];
#pragma unroll
      for (int p = 0; p < 4; ++p) m[p] = lg[p][0];
#pragma unroll
      for (int b = 1; b < 8; ++b)
#pragma unroll
        for (int p = 0; p < 4; ++p) m[p] = fmaxf(m[p], lg[p][b]);
#pragma unroll
      for (int p = 0; p < 4; ++p) s[p] = 0.f;
#pragma unroll
      for (int b = 0; b < 8; ++b)
#pragma unroll
        for (int p = 0; p < 4; ++p) {
          sl[p][b] = __expf(lg[p][b] - m[p]);
          s[p] += sl[p][b];
        }
#pragma unroll
      for (int p = 0; p < 4; ++p) {
        const float ir = __builtin_amdgcn_rcpf(s[p]);   // s >= 1 > 0
#pragma unroll
        for (int b = 0; b < 8; ++b) sl[p][b] *= ir;
      }
    }

    // preds = sum_b votes * sl : lane-local FMA, 4 chains
#pragma unroll
    for (int p = 0; p < 4; ++p) q[p] = (v2f){0.f, 0.f};
#pragma unroll
    for (int b = 0; b < 8; ++b)
#pragma unroll
      for (int p = 0; p < 4; ++p)
        q[p] = __builtin_elementwise_fma((v2f){sl[p][b], sl[p][b]}, v[p][b], q[p]);

    // squash: norm^2 over atoms = reduce over a-lanes (bits 3..5)
    // 8 independent shfl chains (4 px x 2 ch) interleaved
    {
      float n0[4], n1[4];
#pragma unroll
      for (int p = 0; p < 4; ++p) { n0[p] = q[p].x * q[p].x; n1[p] = q[p].y * q[p].y; }
#pragma unroll
      for (int p = 0; p < 4; ++p) { n0[p] += __shfl_xor(n0[p], 8);  n1[p] += __shfl_xor(n1[p], 8); }
#pragma unroll
      for (int p = 0; p < 4; ++p) { n0[p] += __shfl_xor(n0[p], 16); n1[p] += __shfl_xor(n1[p], 16); }
#pragma unroll
      for (int p = 0; p < 4; ++p) { n0[p] += __shfl_xor(n0[p], 32); n1[p] += __shfl_xor(n1[p], 32); }
#pragma unroll
      for (int p = 0; p < 4; ++p) {
        q[p].x *= sqrtf(n0[p]) * __builtin_amdgcn_rcpf(1.f + n0[p]);  // sqrt(n)/(1+n)
        q[p].y *= sqrtf(n1[p]) * __builtin_amdgcn_rcpf(1.f + n1[p]);
      }
    }

    // logits = softmaxed + sum_c votes*preds (reduce over cg-lanes, bits 0..2)
    if (r + 1 < R) {
#pragma unroll
      for (int b = 0; b < 8; ++b) {
        float d[4];
#pragma unroll
        for (int p = 0; p < 4; ++p)
          d[p] = fmaf(v[p][b].x, q[p].x, v[p][b].y * q[p].y);
#pragma unroll
        for (int p = 0; p < 4; ++p) d[p] += __shfl_xor(d[p], 1);
#pragma unroll
        for (int p = 0; p < 4; ++p) d[p] += __shfl_xor(d[p], 2);
#pragma unroll
        for (int p = 0; p < 4; ++p) d[p] += __shfl_xor(d[p], 4);
#pragma unroll
        for (int p = 0; p < 4; ++p) lg[p][b] = sl[p][b] + d[p];
      }
    }
  }
}

__global__ __launch_bounds__(256, 3) void upcaps_tr13(
    const float* __restrict__ xp,    // padded [ci][iy][ixp][b-interleaved]
    const float* __restrict__ wts,
    const int* __restrict__ nroutes,
    float* __restrict__ out)
{
  __shared__ float lds_out[16 * 128];   // 8KB: [pxi][a*16+c]

  const int lane = threadIdx.x & 63;
  const int wid  = threadIdx.x >> 6;
  // bijective XCD swizzle: 2304 tiles = 8 XCDs x 288 contiguous tiles
  const int bid  = blockIdx.x;
  const int tile = (bid & 7) * (NTILES / 8) + (bid >> 3);
  const int oy   = tile / 12;
  const int xg   = (tile - oy * 12) * 16;            // 64B-line aligned
  const int pxb  = (wid & 1) + ((wid >> 1) << 3);    // wave px: pxb + 2j
  const int oxw  = xg + pxb;
  const int a    = lane >> 3;
  const int cg   = lane & 7;
  const int e    = oxw & 1;
  // conv input col: ix = ixb + t + j,  t,j in [0,2]x[0,3]
  const int ixp0 = __builtin_amdgcn_readfirstlane(((oxw - 2 + e) >> 1) + 1);
  const bool use_t2 = (__builtin_amdgcn_readfirstlane(e) == 0);
  const int wlane = a * NC + cg * 2;    // per-lane float offset into w[..][a][c]

  // acc0 = channel c=2cg, acc1 = c=2cg+1; packed over (bp, bp+4)
  v2f acc0[4][4], acc1[4][4];
#pragma unroll
  for (int j = 0; j < 4; ++j)
#pragma unroll
    for (int bp = 0; bp < 4; ++bp) {
      acc0[j][bp] = (v2f){0.f, 0.f};
      acc1[j][bp] = (v2f){0.f, 0.f};
    }

  for (int ky = 0; ky < 5; ++ky) {
    const int py = oy - 2 + ky;
    if (py < 0 || py > 2 * XH - 2 || (py & 1)) continue;   // wave-uniform
    const int iy = py >> 1;
    const float* wk = wts + (ky * 5 + e) * (CIN * NA * NC) + wlane;
#pragma unroll 1
    for (int ci = 0; ci < CIN; ++ci) {
      const float* xrow = xp + ((ci * XH + iy) * WP + ixp0) * 8;  // uniform
      // x columns as v2f b-pairs: col k -> xq2[4k + bp]
      v2f xq2[24];
#pragma unroll
      for (int k = 0; k < 6; ++k) {
        *(float4*)&xq2[4 * k]     = *(const float4*)(xrow + k * 8);
        *(float4*)&xq2[4 * k + 2] = *(const float4*)(xrow + k * 8 + 4);
      }
      // weight splats: loop-invariant for this (ky,ci) -> 6 movs total
      const v2f cw0 = *(const v2f*)(wk + ci * (NA * NC));
      const v2f cw1 = *(const v2f*)(wk + 2 * (CIN * NA * NC) + ci * (NA * NC));
      v2f cw2 = (v2f){0.f, 0.f};
      if (use_t2) cw2 = *(const v2f*)(wk + 4 * (CIN * NA * NC) + ci * (NA * NC));
      const v2f c0x = (v2f){cw0.x, cw0.x}, c0y = (v2f){cw0.y, cw0.y};
      const v2f c1x = (v2f){cw1.x, cw1.x}, c1y = (v2f){cw1.y, cw1.y};
      const v2f c2x = (v2f){cw2.x, cw2.x}, c2y = (v2f){cw2.y, cw2.y};
      // col ir feeds (tap t, px j) with t + j == ir
#pragma unroll
      for (int ir = 0; ir < 6; ++ir) {
        if (ir == 5 && !use_t2) continue;              // odd parity: ir<=4
        if (ir <= 3) {                                 // tap t=0, j=ir
#pragma unroll
          for (int bp = 0; bp < 4; ++bp) {
            const v2f xv = xq2[4 * ir + bp];
            acc0[ir][bp] = __builtin_elementwise_fma(xv, c0x, acc0[ir][bp]);
            acc1[ir][bp] = __builtin_elementwise_fma(xv, c0y, acc1[ir][bp]);
          }
        }
        if (ir >= 1 && ir <= 4) {                      // tap t=1, j=ir-1
#pragma unroll
          for (int bp = 0; bp < 4; ++bp) {
            const v2f xv = xq2[4 * ir + bp];
            acc0[ir-1][bp] = __builtin_elementwise_fma(xv, c1x, acc0[ir-1][bp]);
            acc1[ir-1][bp] = __builtin_elementwise_fma(xv, c1y, acc1[ir-1][bp]);
          }
        }
        if (ir >= 2 && use_t2) {                       // tap t=2, j=ir-2
#pragma unroll
          for (int bp = 0; bp < 4; ++bp) {
            const v2f xv = xq2[4 * ir + bp];
            acc0[ir-2][bp] = __builtin_elementwise_fma(xv, c2x, acc0[ir-2][bp]);
            acc1[ir-2][bp] = __builtin_elementwise_fma(xv, c2y, acc1[ir-2][bp]);
          }
        }
      }
    }
  }

  // -------- repack to routing layout and route all 4 pixels at once --------
  const int R = nroutes[0];
  v2f q[4];
  {
    v2f v[4][8];
#pragma unroll
    for (int j = 0; j < 4; ++j)
#pragma unroll
      for (int bp = 0; bp < 4; ++bp) {
        v[j][bp]     = (v2f){acc0[j][bp].x, acc1[j][bp].x};   // b = bp
        v[j][bp + 4] = (v2f){acc0[j][bp].y, acc1[j][bp].y};   // b = bp+4
      }
    route_quad(v, R, q);
  }

  // -------- stage results to LDS: [pxi][a*16+c] --------
  const int lbase = a * NC + cg * 2;
  *(v2f*)&lds_out[(pxb    ) * 128 + lbase] = q[0];
  *(v2f*)&lds_out[(pxb + 2) * 128 + lbase] = q[1];
  *(v2f*)&lds_out[(pxb + 4) * 128 + lbase] = q[2];
  *(v2f*)&lds_out[(pxb + 6) * 128 + lbase] = q[3];
  __syncthreads();

  // -------- coalesced output: thread -> (row r = a*16+c, half h) --------
  const int t = threadIdx.x;
  const int r = t >> 1, h = t & 1;
  float4 f0, f1;
  f0.x = lds_out[(h * 8 + 0) * 128 + r];
  f0.y = lds_out[(h * 8 + 1) * 128 + r];
  f0.z = lds_out[(h * 8 + 2) * 128 + r];
  f0.w = lds_out[(h * 8 + 3) * 128 + r];
  f1.x = lds_out[(h * 8 + 4) * 128 + r];
  f1.y = lds_out[(h * 8 + 5) * 128 + r];
  f1.z = lds_out[(h * 8 + 6) * 128 + r];
  f1.w = lds_out[(h * 8 + 7) * 128 + r];
  float* op = out + r * (OH * OW) + oy * OW + xg + h * 8;
  *(float4*)op       = f0;
  *(float4*)(op + 4) = f1;
}

extern "C" void kernel_launch(void* const* d_in, const int* in_sizes, int n_in,
                              void* d_out, int out_size, void* d_ws, size_t ws_size,
                              hipStream_t stream) {
  const float* x   = (const float*)d_in[0];
  const float* w   = (const float*)d_in[1];
  const int*   nr  = (const int*)d_in[2];
  float*       out = (float*)d_out;
  float*       xp  = (float*)d_ws;       // needs PADN*4 = 5,013,504 bytes

  pad_x<<<(PADN + 255) / 256, 256, 0, stream>>>(x, xp);
  upcaps_tr13<<<NTILES, 256, 0, stream>>>(xp, w, nr, out);
}

// Round 19
// 126.199 us; speedup vs baseline: 1.7257x; 1.7257x over previous
//
#include <hip/hip_runtime.h>

// UpCaps fused: transposed lanes, b-pair conv, XCD swizzle (R16 = 126.8us
// verified optimum) + vectorized pad_x (R19: one thread per (ci,iy,ixp),
// 8 coalesced read streams + one 32B write; was 1.25M scalar threads).
// STRUCTURAL LEDGER (all measured, do not retry):
//  - occupancy: (256,3)->84 VGPR clean is the ONLY clean point; (256,4)
//    jumps to 64-bucket+spill (R12); (256,5)/(512,8) catastrophic (R10/R11).
//  - LDS x-tile staging: +issue > -latency (R9); with tight caps, spills (R7).
//  - load batching / ci-prefetch: compiler re-sinks loads to consumers,
//    neutral (R13/R17).
//  - v_pk_fma_f32: half-rate fp32 on CDNA4, asm pinning hurts sched (R15).
//  - route_quad (4-px routing): +64 live regs -> scratch spill (R18).
//  - XCD swizzle tile=(bid%8)*288+bid/8: x slice ~1.4MB L2-resident/XCD,
//    FETCH 14.7->6.4MB, -9.2us (R16). KEEP.
// Issue accounting: VALU issue ~76us measured ~= scalar-FMA floor (~58us conv
// + ~12us routing + overhead); remaining 40% is load-latency stall at the
// ledger-capped 3 waves/SIMD. This is the structure's floor.
// lane = a*8 + cg (cg=c/2). Softmax over b lane-local; squash over a-lanes
// (xor 8,16,32); logit update over cg-lanes (xor 1,2,4). Output via 8KB LDS
// transpose -> 64B-line stores.
// Shapes: x(8,16,96,96), w(5,5,16,8,16), out(8,16,192,192).
typedef float v2f __attribute__((ext_vector_type(2)));

#define XH 96
#define XW 96
#define CIN 16
#define NA 8
#define NC 16
#define OH 192
#define OW 192
#define WP 102                        // padded width: ix in [-1,100] -> ixp 0..101
#define NGRP (CIN * XH * WP)          // 156,672 (ci,iy,ixp) groups
#define XB (CIN * XH * XW)            // x batch stride in floats
#define NTILES ((OH * OW) / 16)       // 2304 = 8 XCDs x 288

// one thread per (ci,iy,ixp): reads 8 b-values (coalesced streams), writes
// 32B b-interleaved {b0,b4,b1,b5,b2,b6,b3,b7}
__global__ __launch_bounds__(256) void pad_x(const float* __restrict__ x,
                                             float* __restrict__ xp) {
  int t = blockIdx.x * 256 + threadIdx.x;
  if (t >= NGRP) return;
  int ixp = t % WP;
  int t2  = t / WP;
  int iy  = t2 % XH;
  int ci  = t2 / XH;
  int ix  = ixp - 1;
  float4 lo = {0.f, 0.f, 0.f, 0.f}, hi = {0.f, 0.f, 0.f, 0.f};
  if (ix >= 0 && ix < XW) {
    const float* src = x + (ci * XH + iy) * XW + ix;
    lo.x = src[0 * XB];  lo.y = src[4 * XB];
    lo.z = src[1 * XB];  lo.w = src[5 * XB];
    hi.x = src[2 * XB];  hi.y = src[6 * XB];
    hi.z = src[3 * XB];  hi.w = src[7 * XB];
  }
  float4* dst = (float4*)(xp + t * 8);
  dst[0] = lo;
  dst[1] = hi;
}

// routes two pixels interleaved; va/vb = votes[b] (c-pair) for this lane's
// (a, 2cg..2cg+1). On exit qa/qb hold final squashed preds (c-pair).
__device__ __forceinline__ void route_pair(
    const v2f (&va)[8], const v2f (&vb)[8], int R, v2f& qa, v2f& qb)
{
  float lga[8], lgb[8];
#pragma unroll
  for (int b = 0; b < 8; ++b) { lga[b] = 0.f; lgb[b] = 0.f; }
#pragma unroll 1
  for (int r = 0; r < R; ++r) {
    float sla[8], slb[8];
    if (r == 0) {
#pragma unroll
      for (int b = 0; b < 8; ++b) { sla[b] = 0.125f; slb[b] = 0.125f; }
    } else {
      // softmax over batch: fully lane-local
      float ma = lga[0], mb = lgb[0];
#pragma unroll
      for (int b = 1; b < 8; ++b) { ma = fmaxf(ma, lga[b]); mb = fmaxf(mb, lgb[b]); }
      float sa = 0.f, sb = 0.f;
#pragma unroll
      for (int b = 0; b < 8; ++b) {
        sla[b] = __expf(lga[b] - ma); sa += sla[b];
        slb[b] = __expf(lgb[b] - mb); sb += slb[b];
      }
      const float ira = __builtin_amdgcn_rcpf(sa);   // sa >= 1 > 0
      const float irb = __builtin_amdgcn_rcpf(sb);
#pragma unroll
      for (int b = 0; b < 8; ++b) { sla[b] *= ira; slb[b] *= irb; }
    }

    // preds = sum_b votes * sl : lane-local FMA chain
    qa = (v2f){0.f, 0.f};  qb = (v2f){0.f, 0.f};
#pragma unroll
    for (int b = 0; b < 8; ++b) {
      qa = __builtin_elementwise_fma((v2f){sla[b], sla[b]}, va[b], qa);
      qb = __builtin_elementwise_fma((v2f){slb[b], slb[b]}, vb[b], qb);
    }

    // squash: norm^2 over atoms = reduce over a-lanes (bits 3..5)
    {
      float na0 = qa.x * qa.x, na1 = qa.y * qa.y;
      float nb0 = qb.x * qb.x, nb1 = qb.y * qb.y;
      na0 += __shfl_xor(na0, 8);  na1 += __shfl_xor(na1, 8);
      nb0 += __shfl_xor(nb0, 8);  nb1 += __shfl_xor(nb1, 8);
      na0 += __shfl_xor(na0, 16); na1 += __shfl_xor(na1, 16);
      nb0 += __shfl_xor(nb0, 16); nb1 += __shfl_xor(nb1, 16);
      na0 += __shfl_xor(na0, 32); na1 += __shfl_xor(na1, 32);
      nb0 += __shfl_xor(nb0, 32); nb1 += __shfl_xor(nb1, 32);
      qa.x *= sqrtf(na0) * __builtin_amdgcn_rcpf(1.f + na0);  // sqrt(n)/(1+n)
      qa.y *= sqrtf(na1) * __builtin_amdgcn_rcpf(1.f + na1);
      qb.x *= sqrtf(nb0) * __builtin_amdgcn_rcpf(1.f + nb0);
      qb.y *= sqrtf(nb1) * __builtin_amdgcn_rcpf(1.f + nb1);
    }

    // logits = softmaxed + sum_c votes*preds (reduce over cg-lanes, bits 0..2)
    if (r + 1 < R) {
#pragma unroll
      for (int b = 0; b < 8; ++b) {
        float da = fmaf(va[b].x, qa.x, va[b].y * qa.y);
        float db = fmaf(vb[b].x, qb.x, vb[b].y * qb.y);
        da += __shfl_xor(da, 1);  db += __shfl_xor(db, 1);
        da += __shfl_xor(da, 2);  db += __shfl_xor(db, 2);
        da += __shfl_xor(da, 4);  db += __shfl_xor(db, 4);
        lga[b] = sla[b] + da;     lgb[b] = slb[b] + db;
      }
    }
  }
}

__global__ __launch_bounds__(256, 3) void upcaps_r19(
    const float* __restrict__ xp,    // padded [ci][iy][ixp][b-interleaved]
    const float* __restrict__ wts,
    const int* __restrict__ nroutes,
    float* __restrict__ out)
{
  __shared__ float lds_out[16 * 128];   // 8KB: [pxi][a*16+c]

  const int lane = threadIdx.x & 63;
  const int wid  = threadIdx.x >> 6;
  // bijective XCD swizzle: 2304 tiles = 8 XCDs x 288 contiguous tiles
  const int bid  = blockIdx.x;
  const int tile = (bid & 7) * (NTILES / 8) + (bid >> 3);
  const int oy   = tile / 12;
  const int xg   = (tile - oy * 12) * 16;            // 64B-line aligned
  const int pxb  = (wid & 1) + ((wid >> 1) << 3);    // wave px: pxb + 2j
  const int oxw  = xg + pxb;
  const int a    = lane >> 3;
  const int cg   = lane & 7;
  const int e    = oxw & 1;
  // conv input col: ix = ixb + t + j,  t,j in [0,2]x[0,3]
  const int ixp0 = __builtin_amdgcn_readfirstlane(((oxw - 2 + e) >> 1) + 1);
  const bool use_t2 = (__builtin_amdgcn_readfirstlane(e) == 0);
  const int wlane = a * NC + cg * 2;    // per-lane float offset into w[..][a][c]

  // acc0 = channel c=2cg, acc1 = c=2cg+1; packed over (bp, bp+4)
  v2f acc0[4][4], acc1[4][4];
#pragma unroll
  for (int j = 0; j < 4; ++j)
#pragma unroll
    for (int bp = 0; bp < 4; ++bp) {
      acc0[j][bp] = (v2f){0.f, 0.f};
      acc1[j][bp] = (v2f){0.f, 0.f};
    }

  for (int ky = 0; ky < 5; ++ky) {
    const int py = oy - 2 + ky;
    if (py < 0 || py > 2 * XH - 2 || (py & 1)) continue;   // wave-uniform
    const int iy = py >> 1;
    const float* wk = wts + (ky * 5 + e) * (CIN * NA * NC) + wlane;
#pragma unroll 1
    for (int ci = 0; ci < CIN; ++ci) {
      const float* xrow = xp + ((ci * XH + iy) * WP + ixp0) * 8;  // uniform
      // x columns as v2f b-pairs: col k -> xq2[4k + bp]
      v2f xq2[24];
#pragma unroll
      for (int k = 0; k < 6; ++k) {
        *(float4*)&xq2[4 * k]     = *(const float4*)(xrow + k * 8);
        *(float4*)&xq2[4 * k + 2] = *(const float4*)(xrow + k * 8 + 4);
      }
      // weight splats: loop-invariant for this (ky,ci) -> 6 movs total
      const v2f cw0 = *(const v2f*)(wk + ci * (NA * NC));
      const v2f cw1 = *(const v2f*)(wk + 2 * (CIN * NA * NC) + ci * (NA * NC));
      v2f cw2 = (v2f){0.f, 0.f};
      if (use_t2) cw2 = *(const v2f*)(wk + 4 * (CIN * NA * NC) + ci * (NA * NC));
      const v2f c0x = (v2f){cw0.x, cw0.x}, c0y = (v2f){cw0.y, cw0.y};
      const v2f c1x = (v2f){cw1.x, cw1.x}, c1y = (v2f){cw1.y, cw1.y};
      const v2f c2x = (v2f){cw2.x, cw2.x}, c2y = (v2f){cw2.y, cw2.y};
      // col ir feeds (tap t, px j) with t + j == ir
#pragma unroll
      for (int ir = 0; ir < 6; ++ir) {
        if (ir == 5 && !use_t2) continue;              // odd parity: ir<=4
        if (ir <= 3) {                                 // tap t=0, j=ir
#pragma unroll
          for (int bp = 0; bp < 4; ++bp) {
            const v2f xv = xq2[4 * ir + bp];
            acc0[ir][bp] = __builtin_elementwise_fma(xv, c0x, acc0[ir][bp]);
            acc1[ir][bp] = __builtin_elementwise_fma(xv, c0y, acc1[ir][bp]);
          }
        }
        if (ir >= 1 && ir <= 4) {                      // tap t=1, j=ir-1
#pragma unroll
          for (int bp = 0; bp < 4; ++bp) {
            const v2f xv = xq2[4 * ir + bp];
            acc0[ir-1][bp] = __builtin_elementwise_fma(xv, c1x, acc0[ir-1][bp]);
            acc1[ir-1][bp] = __builtin_elementwise_fma(xv, c1y, acc1[ir-1][bp]);
          }
        }
        if (ir >= 2 && use_t2) {                       // tap t=2, j=ir-2
#pragma unroll
          for (int bp = 0; bp < 4; ++bp) {
            const v2f xv = xq2[4 * ir + bp];
            acc0[ir-2][bp] = __builtin_elementwise_fma(xv, c2x, acc0[ir-2][bp]);
            acc1[ir-2][bp] = __builtin_elementwise_fma(xv, c2y, acc1[ir-2][bp]);
          }
        }
      }
    }
  }

  // -------- repack to routing layout: va[b] = (c0,c1) votes --------
  const int R = nroutes[0];
  v2f q0, q1, q2, q3;
  {
    v2f va[8], vb[8];
#pragma unroll
    for (int bp = 0; bp < 4; ++bp) {
      va[bp]     = (v2f){acc0[0][bp].x, acc1[0][bp].x};   // b = bp
      va[bp + 4] = (v2f){acc0[0][bp].y, acc1[0][bp].y};   // b = bp+4
      vb[bp]     = (v2f){acc0[1][bp].x, acc1[1][bp].x};
      vb[bp + 4] = (v2f){acc0[1][bp].y, acc1[1][bp].y};
    }
    route_pair(va, vb, R, q0, q1);
  }
  {
    v2f va[8], vb[8];
#pragma unroll
    for (int bp = 0; bp < 4; ++bp) {
      va[bp]     = (v2f){acc0[2][bp].x, acc1[2][bp].x};
      va[bp + 4] = (v2f){acc0[2][bp].y, acc1[2][bp].y};
      vb[bp]     = (v2f){acc0[3][bp].x, acc1[3][bp].x};
      vb[bp + 4] = (v2f){acc0[3][bp].y, acc1[3][bp].y};
    }
    route_pair(va, vb, R, q2, q3);
  }

  // -------- stage results to LDS: [pxi][a*16+c] --------
  const int lbase = a * NC + cg * 2;
  *(v2f*)&lds_out[(pxb    ) * 128 + lbase] = q0;
  *(v2f*)&lds_out[(pxb + 2) * 128 + lbase] = q1;
  *(v2f*)&lds_out[(pxb + 4) * 128 + lbase] = q2;
  *(v2f*)&lds_out[(pxb + 6) * 128 + lbase] = q3;
  __syncthreads();

  // -------- coalesced output: thread -> (row r = a*16+c, half h) --------
  const int t = threadIdx.x;
  const int r = t >> 1, h = t & 1;
  float4 f0, f1;
  f0.x = lds_out[(h * 8 + 0) * 128 + r];
  f0.y = lds_out[(h * 8 + 1) * 128 + r];
  f0.z = lds_out[(h * 8 + 2) * 128 + r];
  f0.w = lds_out[(h * 8 + 3) * 128 + r];
  f1.x = lds_out[(h * 8 + 4) * 128 + r];
  f1.y = lds_out[(h * 8 + 5) * 128 + r];
  f1.z = lds_out[(h * 8 + 6) * 128 + r];
  f1.w = lds_out[(h * 8 + 7) * 128 + r];
  float* op = out + r * (OH * OW) + oy * OW + xg + h * 8;
  *(float4*)op       = f0;
  *(float4*)(op + 4) = f1;
}

extern "C" void kernel_launch(void* const* d_in, const int* in_sizes, int n_in,
                              void* d_out, int out_size, void* d_ws, size_t ws_size,
                              hipStream_t stream) {
  const float* x   = (const float*)d_in[0];
  const float* w   = (const float*)d_in[1];
  const int*   nr  = (const int*)d_in[2];
  float*       out = (float*)d_out;
  float*       xp  = (float*)d_ws;       // needs NGRP*8*4 = 5,013,504 bytes

  pad_x<<<(NGRP + 255) / 256, 256, 0, stream>>>(x, xp);
  upcaps_r19<<<NTILES, 256, 0, stream>>>(xp, w, nr, out);
}